// Round 2
// baseline (1221.027 us; speedup 1.0000x reference)
//
#include <hip/hip_runtime.h>
#include <hip/hip_bf16.h>

__device__ __forceinline__ float sigmoidf_(float x){ return 1.f/(1.f+__expf(-x)); }

__device__ __forceinline__ void atomAddF(float* p, float v){
  __hip_atomic_fetch_add(p, v, __ATOMIC_RELAXED, __HIP_MEMORY_SCOPE_AGENT);
}

// ---------------- Edge phase: per-edge GVP + scatter-sum ----------------
// block = 128 threads, thread t = scalar output channel t (t<48 also vector ch)
__global__ __launch_bounds__(128) void edge_kernel(
    const float* __restrict__ edge_s, const float* __restrict__ edge_v,
    const int* __restrict__ dst,
    const float* __restrict__ wes, const float* __restrict__ bes,
    const float* __restrict__ wev, const float* __restrict__ bev,
    float* __restrict__ agg_s, float* __restrict__ agg_v, float* __restrict__ cnt,
    int E)
{
  const int t = threadIdx.x;

  // preload weight row t of wes (32 fp32)
  float w[32];
  #pragma unroll
  for (int k = 0; k < 32; k += 4){
    float4 u = *(const float4*)(wes + t*32 + k);
    w[k+0]=u.x; w[k+1]=u.y; w[k+2]=u.z; w[k+3]=u.w;
  }
  const float bt = bes[t];
  float w0=0.f, w1=0.f, w2=0.f, bv=0.f;
  if (t < 48){
    w0 = wev[t*3+0]; w1 = wev[t*3+1]; w2 = wev[t*3+2];
    bv = bev[t];
  }

  for (int e = blockIdx.x; e < E; e += gridDim.x){
    // broadcast-load edge_s row (128 B); same addr across lanes -> L1 broadcast
    float es[32];
    #pragma unroll
    for (int k = 0; k < 32; k += 4){
      float4 u = *(const float4*)(edge_s + (size_t)e*32 + k);
      es[k+0]=u.x; es[k+1]=u.y; es[k+2]=u.z; es[k+3]=u.w;
    }
    const int d = dst[e];

    float acc = bt;
    #pragma unroll
    for (int k = 0; k < 32; k++) acc += es[k]*w[k];
    const float sil = acc * sigmoidf_(acc);          // silu
    atomAddF(&agg_s[(size_t)d*128 + t], sil);
    if (t == 0) atomAddF(&cnt[d], 1.f);

    // vector part: channels 0..47 all live in wave 0; gate_j = sigmoid(sil_j), j=t/3
    if (t < 64){
      float g = __shfl(sil, (t < 48) ? (t/3) : 0, 64);
      if (t < 48){
        float ex = edge_v[(size_t)e*3+0];
        float ey = edge_v[(size_t)e*3+1];
        float ez = edge_v[(size_t)e*3+2];
        float vv = (bv + w0*ex + w1*ey + w2*ez) * sigmoidf_(g);
        atomAddF(&agg_v[(size_t)d*48 + t], vv);
      }
    }
  }
}

// ---------------- Node phase: LN + vnorm + mean + 4 GEMVs ----------------
// block = 128 threads (2 waves), one node per iteration, thread t = channel
__global__ __launch_bounds__(128) void node_kernel(
    const float* __restrict__ node_s, const float* __restrict__ node_v,
    const float* __restrict__ ln_g, const float* __restrict__ ln_b,
    const float* __restrict__ wns, const float* __restrict__ bns,
    const float* __restrict__ wnv, const float* __restrict__ bnv,
    const float* __restrict__ wrs, const float* __restrict__ brs,
    const float* __restrict__ wrv, const float* __restrict__ brv,
    const float* __restrict__ agg_s, const float* __restrict__ agg_v,
    const float* __restrict__ cnt,
    float* __restrict__ out_s, float* __restrict__ out_v, int N)
{
  const int t = threadIdx.x;
  const int lane = t & 63, wv = t >> 6;

  __shared__ __align__(16) float sh_inS[128];
  __shared__ __align__(16) float sh_sn[128];
  __shared__ __align__(16) float sh_inV[48];
  __shared__ __align__(16) float sh_vn[48];
  __shared__ float red[8];
  __shared__ float sh_gate[16];

  const float lg = ln_g[t];
  const float lb = ln_b[t];

  for (int i = blockIdx.x; i < N; i += gridDim.x){
    float x  = node_s[(size_t)i*128 + t];
    float vv = (t < 48) ? node_v[(size_t)i*48 + t] : 0.f;

    // block reductions: sum(x), sum(x^2), sum(v^2)
    float s1 = x, s2 = x*x, s3 = vv*vv;
    #pragma unroll
    for (int o = 32; o > 0; o >>= 1){
      s1 += __shfl_down(s1, o, 64);
      s2 += __shfl_down(s2, o, 64);
      s3 += __shfl_down(s3, o, 64);
    }
    if (lane == 0){ red[wv] = s1; red[2+wv] = s2; red[4+wv] = s3; }
    __syncthreads();

    const float mean = (red[0]+red[1]) * (1.f/128.f);
    const float ms   = (red[2]+red[3]) * (1.f/128.f);
    const float var  = ms - mean*mean;
    const float rstd = rsqrtf(var + 1e-5f);
    const float rvn  = rsqrtf((red[4]+red[5]) * (1.f/16.f) + 1e-8f);
    const float rdn  = 1.f / fmaxf(cnt[i], 1.f);

    const float sn = (x - mean)*rstd*lg + lb;
    sh_sn[t]  = sn;
    sh_inS[t] = sn + agg_s[(size_t)i*128 + t]*rdn;
    if (t < 48){
      float vn = vv * rvn;
      sh_vn[t]  = vn;
      sh_inV[t] = vn + agg_v[(size_t)i*48 + t]*rdn;
    }
    __syncthreads();

    // scalar dots: wns . inS (silu), wrs . sn (residual)
    const float* wr1 = wns + (size_t)t*128;
    const float* wr2 = wrs + (size_t)t*128;
    float a1 = bns[t];
    float a2 = brs[t];
    #pragma unroll
    for (int k = 0; k < 128; k += 4){
      float4 u1 = *(const float4*)(wr1 + k);
      float4 u2 = *(const float4*)(wr2 + k);
      a1 += sh_inS[k+0]*u1.x + sh_inS[k+1]*u1.y + sh_inS[k+2]*u1.z + sh_inS[k+3]*u1.w;
      a2 += sh_sn[k+0]*u2.x + sh_sn[k+1]*u2.y + sh_sn[k+2]*u2.z + sh_sn[k+3]*u2.w;
    }
    const float sout = a1 * sigmoidf_(a1);   // silu
    out_s[(size_t)i*128 + t] = sout + a2;
    if (t < 16) sh_gate[t] = sigmoidf_(sout);
    __syncthreads();

    // vector dots: wnv . inV (gated), wrv . vn (residual)
    if (t < 48){
      const float* wv1 = wnv + (size_t)t*48;
      const float* wv2 = wrv + (size_t)t*48;
      float b1  = bnv[t];
      float b2r = brv[t];
      #pragma unroll
      for (int k = 0; k < 48; k += 4){
        float4 u1 = *(const float4*)(wv1 + k);
        float4 u2 = *(const float4*)(wv2 + k);
        b1  += sh_inV[k+0]*u1.x + sh_inV[k+1]*u1.y + sh_inV[k+2]*u1.z + sh_inV[k+3]*u1.w;
        b2r += sh_vn[k+0]*u2.x + sh_vn[k+1]*u2.y + sh_vn[k+2]*u2.z + sh_vn[k+3]*u2.w;
      }
      out_v[(size_t)i*48 + t] = b1 * sh_gate[t/3] + b2r;
    }
    __syncthreads();   // protect shared reuse next iteration
  }
}

extern "C" void kernel_launch(void* const* d_in, const int* in_sizes, int n_in,
                              void* d_out, int out_size, void* d_ws, size_t ws_size,
                              hipStream_t stream)
{
  const float* node_s = (const float*)d_in[0];
  const float* node_v = (const float*)d_in[1];
  const int*   eidx   = (const int*)  d_in[2];
  const float* edge_s = (const float*)d_in[3];
  const float* edge_v = (const float*)d_in[4];
  const float* ln_g   = (const float*)d_in[5];
  const float* ln_b   = (const float*)d_in[6];
  const float* wes    = (const float*)d_in[7];
  const float* bes    = (const float*)d_in[8];
  const float* wev    = (const float*)d_in[9];
  const float* bev    = (const float*)d_in[10];
  const float* wns    = (const float*)d_in[11];
  const float* bns    = (const float*)d_in[12];
  const float* wnv    = (const float*)d_in[13];
  const float* bnv    = (const float*)d_in[14];
  const float* wrs    = (const float*)d_in[15];
  const float* brs    = (const float*)d_in[16];
  const float* wrv    = (const float*)d_in[17];
  const float* brv    = (const float*)d_in[18];

  const int N = in_sizes[0] / 128;
  const int E = in_sizes[3] / 32;
  const int* dst = eidx + E;     // edge_index row 1

  // workspace: agg_s [N,128] f32 | agg_v [N,48] f32 | cnt [N] f32
  float* agg_s = (float*)d_ws;
  float* agg_v = agg_s + (size_t)N*128;
  float* cnt   = agg_v + (size_t)N*48;
  hipMemsetAsync(d_ws, 0, (size_t)N*177*sizeof(float), stream);

  edge_kernel<<<4096, 128, 0, stream>>>(edge_s, edge_v, dst,
                                        wes, bes, wev, bev,
                                        agg_s, agg_v, cnt, E);

  float* out_s = (float*)d_out;
  float* out_v = out_s + (size_t)N*128;
  node_kernel<<<2048, 128, 0, stream>>>(node_s, node_v, ln_g, ln_b,
                                        wns, bns, wnv, bnv,
                                        wrs, brs, wrv, brv,
                                        agg_s, agg_v, cnt,
                                        out_s, out_v, N);
}

// Round 5
// 1095.763 us; speedup vs baseline: 1.1143x; 1.1143x over previous
//
#include <hip/hip_runtime.h>

__device__ __forceinline__ float sigmoidf_(float x){ return 1.f/(1.f+__expf(-x)); }

// ---------- CSR build ----------
__global__ void hist_kernel(const int* __restrict__ dst, int* __restrict__ cnt, int E){
  int e = blockIdx.x*blockDim.x + threadIdx.x;
  if (e < E) atomicAdd(&cnt[dst[e]], 1);
}

// cnt and wptr may ALIAS: cnt[i] is read before wptr[i] is written (same thread).
__global__ __launch_bounds__(1024) void scan_kernel(const int* __restrict__ cnt,
                                                    int* __restrict__ off,
                                                    int* __restrict__ wptr, int N){
  __shared__ int part[1024];
  const int t = threadIdx.x;
  const int chunk = (N + 1023) / 1024;
  const int lo = min(t*chunk, N), hi = min(lo+chunk, N);
  int s = 0;
  for (int i = lo; i < hi; i++) s += cnt[i];
  part[t] = s;
  __syncthreads();
  for (int o = 1; o < 1024; o <<= 1){
    int v = (t >= o) ? part[t-o] : 0;
    __syncthreads();
    part[t] += v;
    __syncthreads();
  }
  int run = part[t] - s;              // exclusive prefix for this chunk
  for (int i = lo; i < hi; i++){
    int c = cnt[i];                   // read BEFORE writing (alias-safe)
    off[i] = run; wptr[i] = run;
    run += c;
  }
  if (t == 1023) off[N] = part[1023];
}

__global__ void scatter_kernel(const int* __restrict__ dst, int* __restrict__ wptr,
                               int* __restrict__ csr, int E){
  int e = blockIdx.x*blockDim.x + threadIdx.x;
  if (e < E){
    int pos = atomicAdd(&wptr[dst[e]], 1);
    csr[pos] = e;
  }
}

// ---------- Edge phase: node-centric gather, no float atomics ----------
// block = 128 (thread t = scalar channel), one node per block
__global__ __launch_bounds__(128) void edge_agg_kernel(
    const float* __restrict__ edge_s, const float* __restrict__ edge_v,
    const int* __restrict__ csr, const int* __restrict__ off,
    const float* __restrict__ wes, const float* __restrict__ bes,
    const float* __restrict__ wev, const float* __restrict__ bev,
    float* __restrict__ aggS, float* __restrict__ aggV, int N)
{
  const int t = threadIdx.x;
  float w[32];
  #pragma unroll
  for (int k = 0; k < 32; k += 4){
    float4 u = *(const float4*)(wes + t*32 + k);
    w[k]=u.x; w[k+1]=u.y; w[k+2]=u.z; w[k+3]=u.w;
  }
  const float bt = bes[t];
  float w0=0.f, w1=0.f, w2=0.f, bv=0.f;
  if (t < 48){ w0=wev[t*3]; w1=wev[t*3+1]; w2=wev[t*3+2]; bv=bev[t]; }

  const int i = blockIdx.x;
  if (i >= N) return;
  const int jb = off[i], je = off[i+1];

  float acc_s = 0.f, acc_v = 0.f;
  int e = (jb < je) ? csr[jb] : 0;
  for (int j = jb; j < je; j++){
    const int e_next = (j+1 < je) ? csr[j+1] : 0;   // prefetch next edge id
    const float* er = edge_s + (size_t)e*32;
    float acc = bt;
    #pragma unroll
    for (int k = 0; k < 32; k += 4){
      float4 u = *(const float4*)(er + k);           // broadcast across lanes
      acc += u.x*w[k] + u.y*w[k+1] + u.z*w[k+2] + u.w*w[k+3];
    }
    const float sil = acc * sigmoidf_(acc);          // silu
    acc_s += sil;
    if (t < 64){
      float g = __shfl(sil, (t < 48) ? (t/3) : 0, 64);
      if (t < 48){
        float ex = edge_v[(size_t)e*3+0];
        float ey = edge_v[(size_t)e*3+1];
        float ez = edge_v[(size_t)e*3+2];
        acc_v += (bv + w0*ex + w1*ey + w2*ez) * sigmoidf_(g);
      }
    }
    e = e_next;
  }
  const float rdn = 1.f / (float)max(je - jb, 1);    // scatter-mean
  aggS[(size_t)i*128 + t] = acc_s * rdn;
  if (t < 48) aggV[(size_t)i*48 + t] = acc_v * rdn;
}

// ---------- Node phase: 16 nodes/block, LN fused, register-tiled GEMVs ----------
__global__ __launch_bounds__(256) void node_kernel(
    const float* __restrict__ node_s, const float* __restrict__ node_v,
    const float* __restrict__ ln_g, const float* __restrict__ ln_b,
    const float* __restrict__ wns, const float* __restrict__ bns,
    const float* __restrict__ wnv, const float* __restrict__ bnv,
    const float* __restrict__ wrs, const float* __restrict__ brs,
    const float* __restrict__ wrv, const float* __restrict__ brv,
    const float* __restrict__ aggS, const float* __restrict__ aggV,
    float* __restrict__ out_s, float* __restrict__ out_v, int N)
{
  const int tid = threadIdx.x;
  __shared__ __align__(16) float sh_sn[16][128];
  __shared__ __align__(16) float sh_inS[16][128];
  __shared__ __align__(16) float sh_vn[16][48];
  __shared__ __align__(16) float sh_inV[16][48];
  __shared__ float sh_stat[16][4];    // mean, rstd, rvn
  __shared__ float sh_gate[16][16];

  const int nTiles = (N + 15) / 16;
  for (int tile = blockIdx.x; tile < nTiles; tile += gridDim.x){
    const int i0 = tile * 16;

    // ---- stage scalar+vector rows + LN stats (16 threads per node) ----
    {
      const int n = tid >> 4, l = tid & 15;        // node-in-tile, 16-lane group
      const int node = i0 + n;
      float x[8], ag[8];
      if (node < N){
        const float* ps = node_s + (size_t)node*128 + l*8;
        const float* pa = aggS  + (size_t)node*128 + l*8;
        float4 u0 = *(const float4*)(ps);   float4 u1 = *(const float4*)(ps+4);
        float4 a0 = *(const float4*)(pa);   float4 a1v = *(const float4*)(pa+4);
        x[0]=u0.x;x[1]=u0.y;x[2]=u0.z;x[3]=u0.w;x[4]=u1.x;x[5]=u1.y;x[6]=u1.z;x[7]=u1.w;
        ag[0]=a0.x;ag[1]=a0.y;ag[2]=a0.z;ag[3]=a0.w;ag[4]=a1v.x;ag[5]=a1v.y;ag[6]=a1v.z;ag[7]=a1v.w;
      } else {
        #pragma unroll
        for (int j = 0; j < 8; j++){ x[j]=0.f; ag[j]=0.f; }
      }
      float s1 = 0.f, s2 = 0.f;
      #pragma unroll
      for (int j = 0; j < 8; j++){ s1 += x[j]; s2 += x[j]*x[j]; }

      float vx[3], av[3];
      if (node < N){
        const float* pv = node_v + (size_t)node*48 + l*3;
        const float* pb = aggV  + (size_t)node*48 + l*3;
        vx[0]=pv[0]; vx[1]=pv[1]; vx[2]=pv[2];
        av[0]=pb[0]; av[1]=pb[1]; av[2]=pb[2];
      } else { vx[0]=vx[1]=vx[2]=0.f; av[0]=av[1]=av[2]=0.f; }
      float s3 = vx[0]*vx[0] + vx[1]*vx[1] + vx[2]*vx[2];

      #pragma unroll
      for (int o = 8; o > 0; o >>= 1){
        s1 += __shfl_down(s1, o, 16);
        s2 += __shfl_down(s2, o, 16);
        s3 += __shfl_down(s3, o, 16);
      }
      if (l == 0){
        float mean = s1 * (1.f/128.f);
        float var  = s2 * (1.f/128.f) - mean*mean;
        sh_stat[n][0] = mean;
        sh_stat[n][1] = rsqrtf(var + 1e-5f);
        sh_stat[n][2] = rsqrtf(s3 * (1.f/16.f) + 1e-8f);
      }
      __syncthreads();

      const float mean = sh_stat[n][0], rstd = sh_stat[n][1], rvn = sh_stat[n][2];
      const float* lg = ln_g + l*8;
      const float* lb = ln_b + l*8;
      float4 g0 = *(const float4*)(lg), g1 = *(const float4*)(lg+4);
      float4 b0 = *(const float4*)(lb), b1 = *(const float4*)(lb+4);
      float gg[8] = {g0.x,g0.y,g0.z,g0.w,g1.x,g1.y,g1.z,g1.w};
      float bb[8] = {b0.x,b0.y,b0.z,b0.w,b1.x,b1.y,b1.z,b1.w};
      #pragma unroll
      for (int j = 0; j < 8; j++){
        float sn = (x[j]-mean)*rstd*gg[j] + bb[j];
        sh_sn[n][l*8+j]  = sn;
        sh_inS[n][l*8+j] = sn + ag[j];     // agg already mean-divided
      }
      #pragma unroll
      for (int j = 0; j < 3; j++){
        float vn = vx[j]*rvn;
        sh_vn[n][l*3+j]  = vn;
        sh_inV[n][l*3+j] = vn + av[j];
      }
    }
    __syncthreads();

    // ---- scalar GEMVs: thread = 4 channels x 2 nodes ----
    const int cg = tid & 31, ng = tid >> 5;    // 32 channel-groups, 8 node-groups
    const int n0 = ng*2;
    float a1[4][2] = {{0,0},{0,0},{0,0},{0,0}};
    float a2[4][2] = {{0,0},{0,0},{0,0},{0,0}};
    for (int k = 0; k < 128; k += 4){
      float4 wn4[4], wr4[4];
      #pragma unroll
      for (int j = 0; j < 4; j++){
        wn4[j] = *(const float4*)(wns + (size_t)(cg+32*j)*128 + k);
        wr4[j] = *(const float4*)(wrs + (size_t)(cg+32*j)*128 + k);
      }
      #pragma unroll
      for (int n = 0; n < 2; n++){
        float4 xi = *(const float4*)(&sh_inS[n0+n][k]);
        float4 xs = *(const float4*)(&sh_sn[n0+n][k]);
        #pragma unroll
        for (int j = 0; j < 4; j++){
          a1[j][n] += wn4[j].x*xi.x + wn4[j].y*xi.y + wn4[j].z*xi.z + wn4[j].w*xi.w;
          a2[j][n] += wr4[j].x*xs.x + wr4[j].y*xs.y + wr4[j].z*xs.z + wr4[j].w*xs.w;
        }
      }
    }
    #pragma unroll
    for (int j = 0; j < 4; j++){
      const int c = cg + 32*j;
      const float bn = bns[c], br = brs[c];
      #pragma unroll
      for (int n = 0; n < 2; n++){
        const int node = i0 + n0 + n;
        float a = a1[j][n] + bn;
        float sout = a * sigmoidf_(a);      // silu
        if (node < N) out_s[(size_t)node*128 + c] = sout + a2[j][n] + br;
        if (c < 16) sh_gate[n0+n][c] = sigmoidf_(sout);
      }
    }
    __syncthreads();

    // ---- vector GEMVs: 192 threads = 48 channels x 4 node-groups ----
    if (tid < 192){
      const int vc = tid % 48, vg = tid / 48;
      const int nb = vg*4;
      float b1[4] = {0,0,0,0}, b2[4] = {0,0,0,0};
      for (int k = 0; k < 48; k += 4){
        float4 w1 = *(const float4*)(wnv + (size_t)vc*48 + k);
        float4 w2 = *(const float4*)(wrv + (size_t)vc*48 + k);
        #pragma unroll
        for (int n = 0; n < 4; n++){
          float4 xi = *(const float4*)(&sh_inV[nb+n][k]);
          float4 xs = *(const float4*)(&sh_vn[nb+n][k]);
          b1[n] += w1.x*xi.x + w1.y*xi.y + w1.z*xi.z + w1.w*xi.w;
          b2[n] += w2.x*xs.x + w2.y*xs.y + w2.z*xs.z + w2.w*xs.w;
        }
      }
      const float bb1 = bnv[vc], bb2 = brv[vc];
      const int go = vc/3;
      #pragma unroll
      for (int n = 0; n < 4; n++){
        const int node = i0 + nb + n;
        if (node < N)
          out_v[(size_t)node*48 + vc] = (b1[n]+bb1)*sh_gate[nb+n][go] + b2[n] + bb2;
      }
    }
    __syncthreads();   // protect LDS reuse next tile
  }
}

extern "C" void kernel_launch(void* const* d_in, const int* in_sizes, int n_in,
                              void* d_out, int out_size, void* d_ws, size_t ws_size,
                              hipStream_t stream)
{
  const float* node_s = (const float*)d_in[0];
  const float* node_v = (const float*)d_in[1];
  const int*   eidx   = (const int*)  d_in[2];
  const float* edge_s = (const float*)d_in[3];
  const float* edge_v = (const float*)d_in[4];
  const float* ln_g   = (const float*)d_in[5];
  const float* ln_b   = (const float*)d_in[6];
  const float* wes    = (const float*)d_in[7];
  const float* bes    = (const float*)d_in[8];
  const float* wev    = (const float*)d_in[9];
  const float* bev    = (const float*)d_in[10];
  const float* wns    = (const float*)d_in[11];
  const float* bns    = (const float*)d_in[12];
  const float* wnv    = (const float*)d_in[13];
  const float* bnv    = (const float*)d_in[14];
  const float* wrs    = (const float*)d_in[15];
  const float* brs    = (const float*)d_in[16];
  const float* wrv    = (const float*)d_in[17];
  const float* brv    = (const float*)d_in[18];

  const int N = in_sizes[0] / 128;
  const int E = in_sizes[3] / 32;
  const int* dst = eidx + E;     // edge_index row 1

  // agg arrays live in d_ws: N*176*4 = 35.2 MB (< R2's proven-safe 35.4 MB).
  float* aggS = (float*)d_ws;
  float* aggV = aggS + (size_t)N*128;

  // CSR scratch lives in the FRONT of d_out (3.6 MB of its 35.2 MB).
  // Lifetime: built by hist/scan/scatter, consumed by edge_agg_kernel, all
  // strictly before node_kernel overwrites d_out with final results.
  int* off  = (int*)d_out;
  int* wptr = off + (N + 1);
  int* csr  = wptr + N;

  hipMemsetAsync(wptr, 0, (size_t)N*sizeof(int), stream);
  hist_kernel<<<(E+255)/256, 256, 0, stream>>>(dst, wptr, E);
  scan_kernel<<<1, 1024, 0, stream>>>(wptr, off, wptr, N);
  scatter_kernel<<<(E+255)/256, 256, 0, stream>>>(dst, wptr, csr, E);

  edge_agg_kernel<<<N, 128, 0, stream>>>(edge_s, edge_v, csr, off,
                                         wes, bes, wev, bev, aggS, aggV, N);

  float* out_s = (float*)d_out;
  float* out_v = out_s + (size_t)N*128;
  node_kernel<<<(N+15)/16, 256, 0, stream>>>(node_s, node_v, ln_g, ln_b,
                                             wns, bns, wnv, bnv,
                                             wrs, brs, wrv, brv,
                                             aggS, aggV, out_s, out_v, N);
}

// Round 6
// 945.376 us; speedup vs baseline: 1.2916x; 1.1591x over previous
//
#include <hip/hip_runtime.h>

__device__ __forceinline__ float sigmoidf_(float x){ return 1.f/(1.f+__expf(-x)); }

// ---------- CSR build (proven in R5) ----------
__global__ void hist_kernel(const int* __restrict__ dst, int* __restrict__ cnt, int E){
  int e = blockIdx.x*blockDim.x + threadIdx.x;
  if (e < E) atomicAdd(&cnt[dst[e]], 1);
}

// cnt and wptr may ALIAS: cnt[i] read before wptr[i] written (same thread).
__global__ __launch_bounds__(1024) void scan_kernel(const int* __restrict__ cnt,
                                                    int* __restrict__ off,
                                                    int* __restrict__ wptr, int N){
  __shared__ int part[1024];
  const int t = threadIdx.x;
  const int chunk = (N + 1023) / 1024;
  const int lo = min(t*chunk, N), hi = min(lo+chunk, N);
  int s = 0;
  for (int i = lo; i < hi; i++) s += cnt[i];
  part[t] = s;
  __syncthreads();
  for (int o = 1; o < 1024; o <<= 1){
    int v = (t >= o) ? part[t-o] : 0;
    __syncthreads();
    part[t] += v;
    __syncthreads();
  }
  int run = part[t] - s;
  for (int i = lo; i < hi; i++){
    int c = cnt[i];
    off[i] = run; wptr[i] = run;
    run += c;
  }
  if (t == 1023) off[N] = part[1023];
}

__global__ void scatter_kernel(const int* __restrict__ dst, int* __restrict__ wptr,
                               int* __restrict__ csr, int E){
  int e = blockIdx.x*blockDim.x + threadIdx.x;
  if (e < E){
    int pos = atomicAdd(&wptr[dst[e]], 1);
    csr[pos] = e;
  }
}

// ---------- Edge phase v2: node-centric gather, depth-1 row prefetch ----------
__global__ __launch_bounds__(128) void edge_agg_kernel(
    const float* __restrict__ edge_s, const float* __restrict__ edge_v,
    const int* __restrict__ csr, const int* __restrict__ off,
    const float* __restrict__ wes, const float* __restrict__ bes,
    const float* __restrict__ wev, const float* __restrict__ bev,
    float* __restrict__ aggS, float* __restrict__ aggV, int N)
{
  const int t = threadIdx.x;
  float w[32];
  #pragma unroll
  for (int k = 0; k < 32; k += 4){
    float4 u = *(const float4*)(wes + t*32 + k);
    w[k]=u.x; w[k+1]=u.y; w[k+2]=u.z; w[k+3]=u.w;
  }
  const float bt = bes[t];
  const bool w0 = (t < 64);
  float wv0=0.f, wv1=0.f, wv2=0.f, bv=0.f;
  if (t < 48){ wv0=wev[t*3]; wv1=wev[t*3+1]; wv2=wev[t*3+2]; bv=bev[t]; }

  const int i = blockIdx.x;
  if (i >= N) return;
  const int jb = off[i], je = off[i+1];

  float accS = 0.f, accV = 0.f;
  if (jb < je){
    int e = csr[jb];
    float4 cur[8];
    {
      const float4* pr = (const float4*)(edge_s + (size_t)e*32);
      #pragma unroll
      for (int q = 0; q < 8; q++) cur[q] = pr[q];
    }
    float vx=0.f, vy=0.f, vz=0.f;
    if (w0){ const float* pv = edge_v + (size_t)e*3; vx=pv[0]; vy=pv[1]; vz=pv[2]; }

    for (int j = jb; j < je; j++){
      const int en = (j+1 < je) ? csr[j+1] : e;
      // issue prefetch of next row FIRST (overlaps with compute below)
      float4 nxt[8];
      {
        const float4* pn = (const float4*)(edge_s + (size_t)en*32);
        #pragma unroll
        for (int q = 0; q < 8; q++) nxt[q] = pn[q];
      }
      float nx=0.f, ny=0.f, nz=0.f;
      if (w0){ const float* pv = edge_v + (size_t)en*3; nx=pv[0]; ny=pv[1]; nz=pv[2]; }

      // compute on current row: two independent partial chains
      float d0 = 0.f, d1 = 0.f;
      #pragma unroll
      for (int q = 0; q < 8; q += 2){
        d0 += cur[q].x*w[4*q+0] + cur[q].y*w[4*q+1] + cur[q].z*w[4*q+2] + cur[q].w*w[4*q+3];
        d1 += cur[q+1].x*w[4*q+4] + cur[q+1].y*w[4*q+5] + cur[q+1].z*w[4*q+6] + cur[q+1].w*w[4*q+7];
      }
      const float acc = bt + d0 + d1;
      const float sil = acc * sigmoidf_(acc);      // silu
      accS += sil;
      if (w0){
        float g = __shfl(sil, (t < 48) ? (t/3) : 0, 64);
        if (t < 48) accV += (bv + wv0*vx + wv1*vy + wv2*vz) * sigmoidf_(g);
      }
      #pragma unroll
      for (int q = 0; q < 8; q++) cur[q] = nxt[q];
      vx=nx; vy=ny; vz=nz;
    }
  }
  const float rdn = 1.f / (float)max(je - jb, 1);  // scatter-mean
  aggS[(size_t)i*128 + t] = accS * rdn;
  if (t < 48) aggV[(size_t)i*48 + t] = accV * rdn;
}

// ---------- Node phase: fused LN + GEMVs, nodes-in-lanes ----------
// block = 256 thr, tile = 32 nodes. lane&31 = node-in-tile; weight addresses
// are uniform per half-wave (2 cachelines/instr vs 32 in the R5 layout).
#define RS 130   // LDS row stride for 128-ch arrays (2-way conflicts only)
#define RV 50    // LDS row stride for 48-ch arrays
__global__ __launch_bounds__(256) void node_kernel(
    const float* __restrict__ node_s, const float* __restrict__ node_v,
    const float* __restrict__ ln_g, const float* __restrict__ ln_b,
    const float* __restrict__ wns, const float* __restrict__ bns,
    const float* __restrict__ wnv, const float* __restrict__ bnv,
    const float* __restrict__ wrs, const float* __restrict__ brs,
    const float* __restrict__ wrv, const float* __restrict__ brv,
    const float* __restrict__ aggS, const float* __restrict__ aggV,
    float* __restrict__ out_s, float* __restrict__ out_v, int N)
{
  const int tid = threadIdx.x;
  const int i0  = blockIdx.x * 32;

  __shared__ float shA[32*RS];   // raw node_s, then inS = sn + aggS
  __shared__ float shS[32*RS];   // sn
  __shared__ float shV[32*RV];   // inV = vn + aggV
  __shared__ float shW[32*RV];   // raw node_v, then vn
  __shared__ float shMean[32], shRstd[32], shRvn[32];
  __shared__ float shGate[32*16];

  // ---- pass 1: coalesced stage (zero-pad past N) ----
  #pragma unroll
  for (int q = 0; q < 4; q++){                 // 32x128 floats
    const int flat = q*1024 + tid*4;
    const int n = flat >> 7, k = flat & 127;
    float4 v = make_float4(0.f,0.f,0.f,0.f);
    if (i0 + n < N) v = *(const float4*)(node_s + (size_t)(i0+n)*128 + k);
    float* p = &shA[n*RS + k];
    ((float2*)p)[0] = make_float2(v.x, v.y);
    ((float2*)p)[1] = make_float2(v.z, v.w);
  }
  {                                            // 32x48 floats: thread t -> n=t/8, k=(t%8)*6
    const int n = tid >> 3, k = (tid & 7)*6;
    float vv[6] = {0,0,0,0,0,0};
    if (i0 + n < N){
      const float* pv = node_v + (size_t)(i0+n)*48 + k;
      #pragma unroll
      for (int m = 0; m < 6; m++) vv[m] = pv[m];
    }
    #pragma unroll
    for (int m = 0; m < 6; m += 2)
      *(float2*)&shW[n*RV + k + m] = make_float2(vv[m], vv[m+1]);
  }
  __syncthreads();

  // ---- stats: wave0 lanes 0-31 scalar LN, lanes 32-63 vector norm ----
  if (tid < 32){
    const int n = tid;
    float s1 = 0.f, s2 = 0.f;
    #pragma unroll 8
    for (int j = 0; j < 64; j++){
      float2 v = *(const float2*)&shA[n*RS + 2*j];
      s1 += v.x + v.y; s2 += v.x*v.x + v.y*v.y;
    }
    float mean = s1 * (1.f/128.f);
    float var  = s2 * (1.f/128.f) - mean*mean;
    shMean[n] = mean;
    shRstd[n] = rsqrtf(var + 1e-5f);
  } else if (tid < 64){
    const int n = tid - 32;
    float s3 = 0.f;
    #pragma unroll 8
    for (int j = 0; j < 24; j++){
      float2 v = *(const float2*)&shW[n*RV + 2*j];
      s3 += v.x*v.x + v.y*v.y;
    }
    shRvn[n] = rsqrtf(s3 * (1.f/16.f) + 1e-8f);
  }
  __syncthreads();

  // ---- pass 3: normalize + add agg (same-thread in-place, barrier-separated) ----
  #pragma unroll
  for (int q = 0; q < 4; q++){
    const int flat = q*1024 + tid*4;
    const int n = flat >> 7, k = flat & 127;
    const float m = shMean[n], r = shRstd[n];
    float* p = &shA[n*RS + k];
    float2 x01 = ((float2*)p)[0], x23 = ((float2*)p)[1];
    float4 g = *(const float4*)(ln_g + k);
    float4 b = *(const float4*)(ln_b + k);
    float sn0 = (x01.x - m)*r*g.x + b.x;
    float sn1 = (x01.y - m)*r*g.y + b.y;
    float sn2 = (x23.x - m)*r*g.z + b.z;
    float sn3 = (x23.y - m)*r*g.w + b.w;
    float4 a = make_float4(0.f,0.f,0.f,0.f);
    if (i0 + n < N) a = *(const float4*)(aggS + (size_t)(i0+n)*128 + k);
    float* ps = &shS[n*RS + k];
    ((float2*)ps)[0] = make_float2(sn0, sn1);
    ((float2*)ps)[1] = make_float2(sn2, sn3);
    ((float2*)p)[0] = make_float2(sn0 + a.x, sn1 + a.y);
    ((float2*)p)[1] = make_float2(sn2 + a.z, sn3 + a.w);
  }
  {
    const int n = tid >> 3, k = (tid & 7)*6;
    const float rv = shRvn[n];
    float a[6] = {0,0,0,0,0,0};
    if (i0 + n < N){
      const float* pa = aggV + (size_t)(i0+n)*48 + k;
      #pragma unroll
      for (int m = 0; m < 6; m++) a[m] = pa[m];
    }
    #pragma unroll
    for (int m = 0; m < 6; m += 2){
      float2 raw = *(float2*)&shW[n*RV + k + m];
      float vn0 = raw.x * rv, vn1 = raw.y * rv;
      *(float2*)&shW[n*RV + k + m] = make_float2(vn0, vn1);
      *(float2*)&shV[n*RV + k + m] = make_float2(vn0 + a[m], vn1 + a[m+1]);
    }
  }
  __syncthreads();

  // ---- scalar GEMVs: wave covers 32 channels (16 per half-wave), lane = node ----
  const int wave = tid >> 6, lane = tid & 63;
  const int sub = lane >> 5, n = lane & 31;
  const int nodeG = i0 + n;
  const int cb = wave*32 + sub*16;

  #pragma unroll
  for (int jg = 0; jg < 4; jg++){
    const int c0 = cb + jg*4;
    float acc1[4] = {0,0,0,0}, acc2[4] = {0,0,0,0};
    for (int kb = 0; kb < 128; kb += 8){
      const float* pa = &shA[n*RS + kb];
      const float* ps = &shS[n*RS + kb];
      float2 a0 = ((const float2*)pa)[0], a1 = ((const float2*)pa)[1];
      float2 a2 = ((const float2*)pa)[2], a3 = ((const float2*)pa)[3];
      float2 s0 = ((const float2*)ps)[0], s1 = ((const float2*)ps)[1];
      float2 s2 = ((const float2*)ps)[2], s3 = ((const float2*)ps)[3];
      #pragma unroll
      for (int j = 0; j < 4; j++){
        const float* w1 = wns + (size_t)(c0+j)*128 + kb;
        const float* w2 = wrs + (size_t)(c0+j)*128 + kb;
        float4 u0 = *(const float4*)w1, u1 = *(const float4*)(w1+4);
        float4 y0 = *(const float4*)w2, y1 = *(const float4*)(w2+4);
        acc1[j] += a0.x*u0.x + a0.y*u0.y + a1.x*u0.z + a1.y*u0.w
                 + a2.x*u1.x + a2.y*u1.y + a3.x*u1.z + a3.y*u1.w;
        acc2[j] += s0.x*y0.x + s0.y*y0.y + s1.x*y0.z + s1.y*y0.w
                 + s2.x*y1.x + s2.y*y1.y + s3.x*y1.z + s3.y*y1.w;
      }
    }
    #pragma unroll
    for (int j = 0; j < 4; j++){
      const int c = c0 + j;
      float aa = acc1[j] + bns[c];
      float so = aa * sigmoidf_(aa);            // silu
      if (c < 16) shGate[n*16 + c] = sigmoidf_(so);
      if (nodeG < N) out_s[(size_t)nodeG*128 + c] = so + acc2[j] + brs[c];
    }
  }
  __syncthreads();   // gate ready

  // ---- vector GEMVs: 6 channels per half-wave-slot, lane = node ----
  const int vb = wave*12 + sub*6;
  {
    float acc1[6] = {0,0,0,0,0,0}, acc2[6] = {0,0,0,0,0,0};
    for (int kb = 0; kb < 48; kb += 8){
      const float* pa = &shV[n*RV + kb];
      const float* ps = &shW[n*RV + kb];
      float2 a0 = ((const float2*)pa)[0], a1 = ((const float2*)pa)[1];
      float2 a2 = ((const float2*)pa)[2], a3 = ((const float2*)pa)[3];
      float2 s0 = ((const float2*)ps)[0], s1 = ((const float2*)ps)[1];
      float2 s2 = ((const float2*)ps)[2], s3 = ((const float2*)ps)[3];
      #pragma unroll
      for (int j = 0; j < 6; j++){
        const float* w1 = wnv + (size_t)(vb+j)*48 + kb;
        const float* w2 = wrv + (size_t)(vb+j)*48 + kb;
        float4 u0 = *(const float4*)w1, u1 = *(const float4*)(w1+4);
        float4 y0 = *(const float4*)w2, y1 = *(const float4*)(w2+4);
        acc1[j] += a0.x*u0.x + a0.y*u0.y + a1.x*u0.z + a1.y*u0.w
                 + a2.x*u1.x + a2.y*u1.y + a3.x*u1.z + a3.y*u1.w;
        acc2[j] += s0.x*y0.x + s0.y*y0.y + s1.x*y0.z + s1.y*y0.w
                 + s2.x*y1.x + s2.y*y1.y + s3.x*y1.z + s3.y*y1.w;
      }
    }
    if (nodeG < N){
      #pragma unroll
      for (int j = 0; j < 6; j++){
        const int c = vb + j;
        float g = shGate[n*16 + c/3];
        out_v[(size_t)nodeG*48 + c] = (acc1[j] + bnv[c])*g + acc2[j] + brv[c];
      }
    }
  }
}

extern "C" void kernel_launch(void* const* d_in, const int* in_sizes, int n_in,
                              void* d_out, int out_size, void* d_ws, size_t ws_size,
                              hipStream_t stream)
{
  const float* node_s = (const float*)d_in[0];
  const float* node_v = (const float*)d_in[1];
  const int*   eidx   = (const int*)  d_in[2];
  const float* edge_s = (const float*)d_in[3];
  const float* edge_v = (const float*)d_in[4];
  const float* ln_g   = (const float*)d_in[5];
  const float* ln_b   = (const float*)d_in[6];
  const float* wes    = (const float*)d_in[7];
  const float* bes    = (const float*)d_in[8];
  const float* wev    = (const float*)d_in[9];
  const float* bev    = (const float*)d_in[10];
  const float* wns    = (const float*)d_in[11];
  const float* bns    = (const float*)d_in[12];
  const float* wnv    = (const float*)d_in[13];
  const float* bnv    = (const float*)d_in[14];
  const float* wrs    = (const float*)d_in[15];
  const float* brs    = (const float*)d_in[16];
  const float* wrv    = (const float*)d_in[17];
  const float* brv    = (const float*)d_in[18];

  const int N = in_sizes[0] / 128;
  const int E = in_sizes[3] / 32;
  const int* dst = eidx + E;     // edge_index row 1

  // agg arrays in d_ws: N*176*4 = 35.2 MB (proven-safe footprint).
  float* aggS = (float*)d_ws;
  float* aggV = aggS + (size_t)N*128;

  // CSR scratch in the FRONT of d_out (3.6 MB); dead before node_kernel writes.
  int* off  = (int*)d_out;
  int* wptr = off + (N + 1);
  int* csr  = wptr + N;

  hipMemsetAsync(wptr, 0, (size_t)N*sizeof(int), stream);
  hist_kernel<<<(E+255)/256, 256, 0, stream>>>(dst, wptr, E);
  scan_kernel<<<1, 1024, 0, stream>>>(wptr, off, wptr, N);
  scatter_kernel<<<(E+255)/256, 256, 0, stream>>>(dst, wptr, csr, E);

  edge_agg_kernel<<<N, 128, 0, stream>>>(edge_s, edge_v, csr, off,
                                         wes, bes, wev, bev, aggS, aggV, N);

  float* out_s = (float*)d_out;
  float* out_v = out_s + (size_t)N*128;
  node_kernel<<<(N+31)/32, 256, 0, stream>>>(node_s, node_v, ln_g, ln_b,
                                             wns, bns, wnv, bnv,
                                             wrs, brs, wrv, brv,
                                             aggS, aggV, out_s, out_v, N);
}